// Round 1
// baseline (800.129 us; speedup 1.0000x reference)
//
#include <hip/hip_runtime.h>

#define D 768
#define CAP 64      // max layer-2 in-edges per target
#define MAXDEG 128  // max in-degree of any processed node (layer 1)
#define NEG 0.2f

__device__ __forceinline__ float block_reduce_sum(float v, float* scratch) {
    int lane = threadIdx.x & 63;
    int wid  = threadIdx.x >> 6;
    #pragma unroll
    for (int o = 32; o > 0; o >>= 1) v += __shfl_down(v, o, 64);
    if (lane == 0) scratch[wid] = v;
    __syncthreads();
    if (threadIdx.x == 0) {
        float r = 0.f;
        int nw = (blockDim.x + 63) >> 6;
        for (int w = 0; w < nw; ++w) r += scratch[w];
        scratch[0] = r;
    }
    __syncthreads();
    float r = scratch[0];
    __syncthreads();
    return r;
}

// v[which*D + i] = sum_j W[i*D+j] * a[j]  for the 6 (W, a) pairs
__global__ void projvec(const float* W1, const float* We1, const float* W2, const float* We2,
                        const float* al1, const float* ar1, const float* ae1,
                        const float* al2, const float* ar2, const float* ae2,
                        float* v) {
    int task = blockIdx.x * (blockDim.x >> 6) + (threadIdx.x >> 6);
    int lane = threadIdx.x & 63;
    if (task >= 6 * D) return;
    int which = task / D, i = task % D;
    const float* W; const float* a;
    switch (which) {
        case 0: W = W1;  a = al1; break;
        case 1: W = W1;  a = ar1; break;
        case 2: W = We1; a = ae1; break;
        case 3: W = W2;  a = al2; break;
        case 4: W = W2;  a = ar2; break;
        default: W = We2; a = ae2; break;
    }
    float s = 0.f;
    for (int j = lane; j < D; j += 64) s += W[i * D + j] * a[j];
    #pragma unroll
    for (int o = 32; o > 0; o >>= 1) s += __shfl_down(s, o, 64);
    if (lane == 0) v[which * D + i] = s;
}

// wave w finds, in edge-index order, the edges with dst == graph_offsets[w]
__global__ void build_l2(const int* __restrict__ dst, const int* __restrict__ goff,
                         int E, int* l2e, int* cnt) {
    int w = threadIdx.x >> 6, lane = threadIdx.x & 63;
    int t = goff[w];
    int base = 0;
    for (int eb = 0; eb < E; eb += 64) {
        int e = eb + lane;
        bool p = (e < E) && (dst[e] == t);
        unsigned long long m = __ballot(p);
        if (p) {
            int pos = base + __popcll(m & ((1ULL << lane) - 1));
            if (pos < CAP) l2e[w * CAP + pos] = e;
        }
        base += __popcll(m);
    }
    if (lane == 0) cnt[w] = base < CAP ? base : CAP;
}

// one block per needed layer-1 output row (targets, then L2-edge srcs)
__global__ __launch_bounds__(256) void layer1(
        const float* __restrict__ x, const float* __restrict__ ef,
        const int* __restrict__ src, const int* __restrict__ dst,
        const int* __restrict__ goff,
        const float* __restrict__ W1, const float* __restrict__ We1,
        const float* __restrict__ b1, const float* __restrict__ v,
        const int* __restrict__ l2e, const int* __restrict__ cnt,
        float* h_t, float* h_s, int E, int B) {
    __shared__ float xj[D], sc[D], ec[D];
    __shared__ float red[8];
    __shared__ int   mlist[MAXDEG], msrc[MAXDEG];
    __shared__ float matt[MAXDEG];
    __shared__ int   nm_sh;
    int tid = threadIdx.x;
    int bid = blockIdx.x;
    int j; float* hout;
    if (bid < B) {
        j = goff[bid]; hout = h_t + bid * D;
    } else {
        int flat = bid - B; int b = flat >> 6, i = flat & 63;
        if (b >= B || i >= cnt[b]) return;
        j = src[l2e[b * CAP + i]];
        hout = h_s + (long)flat * D;
    }
    const float* val1 = v;
    const float* var1 = v + D;
    const float* vae1 = v + 2 * D;

    for (int c = tid; c < D; c += 256) xj[c] = x[(long)j * D + c];
    if (tid == 0) nm_sh = 0;
    __syncthreads();

    float p = 0.f;
    for (int c = tid; c < D; c += 256) p += xj[c] * var1[c];
    float er_j = block_reduce_sum(p, red);

    for (int e = tid; e < E; e += 256)
        if (dst[e] == j) { int q = atomicAdd(&nm_sh, 1); if (q < MAXDEG) mlist[q] = e; }
    __syncthreads();
    int nm = nm_sh < MAXDEG ? nm_sh : MAXDEG;
    if (tid == 0) {  // sort by edge id -> deterministic order
        for (int a_ = 1; a_ < nm; ++a_) {
            int key = mlist[a_]; int bq = a_ - 1;
            while (bq >= 0 && mlist[bq] > key) { mlist[bq + 1] = mlist[bq]; --bq; }
            mlist[bq + 1] = key;
        }
        for (int k = 0; k < nm; ++k) msrc[k] = src[mlist[k]];
    }
    __syncthreads();

    for (int k = 0; k < nm; ++k) {
        int e = mlist[k], s_ = msrc[k];
        float q = 0.f;
        for (int c = tid; c < D; c += 256)
            q += x[(long)s_ * D + c] * val1[c] + ef[(long)e * D + c] * vae1[c];
        float tot = block_reduce_sum(q, red);
        if (tid == 0) {
            tot += er_j;
            matt[k] = tot >= 0.f ? tot : NEG * tot;
        }
        __syncthreads();
    }
    if (tid == 0) {
        float m = -1e30f;
        for (int k = 0; k < nm; ++k) m = fmaxf(m, matt[k]);
        float s = 0.f;
        for (int k = 0; k < nm; ++k) { matt[k] = expf(matt[k] - m); s += matt[k]; }
        float inv = 1.f / s;
        for (int k = 0; k < nm; ++k) matt[k] *= inv;
    }
    __syncthreads();

    for (int c = tid; c < D; c += 256) {
        float sx = 0.f, se = 0.f;
        for (int k = 0; k < nm; ++k) {
            sx += matt[k] * x[(long)msrc[k] * D + c];
            se += matt[k] * ef[(long)mlist[k] * D + c];
        }
        sc[c] = sx; ec[c] = se;
    }
    __syncthreads();

    float a0 = 0.f, a1 = 0.f, a2 = 0.f;
    int c0 = tid, c1 = tid + 256, c2 = tid + 512;
    for (int i = 0; i < D; ++i) {
        float sx = sc[i], se = ec[i];
        const float* r1 = W1 + (long)i * D;
        const float* r2 = We1 + (long)i * D;
        a0 += sx * r1[c0] + se * r2[c0];
        a1 += sx * r1[c1] + se * r2[c1];
        a2 += sx * r1[c2] + se * r2[c2];
    }
    float h0 = a0 + xj[c0] + b1[c0]; hout[c0] = h0 > 0.f ? h0 : 0.f;
    float h1 = a1 + xj[c1] + b1[c1]; hout[c1] = h1 > 0.f ? h1 : 0.f;
    float h2 = a2 + xj[c2] + b1[c2]; hout[c2] = h2 > 0.f ? h2 : 0.f;
}

// one block per target: layer-2 attention + aggregate + residual + bias -> d_out
__global__ __launch_bounds__(256) void layer2(
        const float* __restrict__ ef,
        const float* __restrict__ W2, const float* __restrict__ We2,
        const float* __restrict__ b2, const float* __restrict__ v,
        const int* __restrict__ l2e, const int* __restrict__ cnt,
        const float* __restrict__ h_t, const float* __restrict__ h_s,
        float* out, int B) {
    __shared__ float ht[D], sc[D], ec[D];
    __shared__ float red[8];
    __shared__ float matt[CAP];
    int tid = threadIdx.x, b = blockIdx.x;
    const float* val2 = v + 3 * D;
    const float* var2 = v + 4 * D;
    const float* vae2 = v + 5 * D;

    for (int c = tid; c < D; c += 256) ht[c] = h_t[b * D + c];
    __syncthreads();

    float p = 0.f;
    for (int c = tid; c < D; c += 256) p += ht[c] * var2[c];
    float er2 = block_reduce_sum(p, red);

    int deg = cnt[b];
    for (int k = 0; k < deg; ++k) {
        int e = l2e[b * CAP + k];
        const float* hs = h_s + (long)(b * CAP + k) * D;
        float q = 0.f;
        for (int c = tid; c < D; c += 256)
            q += hs[c] * val2[c] + ef[(long)e * D + c] * vae2[c];
        float tot = block_reduce_sum(q, red);
        if (tid == 0) {
            tot += er2;
            matt[k] = tot >= 0.f ? tot : NEG * tot;
        }
        __syncthreads();
    }
    if (tid == 0) {
        float m = -1e30f;
        for (int k = 0; k < deg; ++k) m = fmaxf(m, matt[k]);
        float s = 0.f;
        for (int k = 0; k < deg; ++k) { matt[k] = expf(matt[k] - m); s += matt[k]; }
        float inv = 1.f / s;
        for (int k = 0; k < deg; ++k) matt[k] *= inv;
    }
    __syncthreads();

    for (int c = tid; c < D; c += 256) {
        float sx = 0.f, se = 0.f;
        for (int k = 0; k < deg; ++k) {
            sx += matt[k] * h_s[(long)(b * CAP + k) * D + c];
            se += matt[k] * ef[(long)l2e[b * CAP + k] * D + c];
        }
        sc[c] = sx; ec[c] = se;
    }
    __syncthreads();

    float a0 = 0.f, a1 = 0.f, a2 = 0.f;
    int c0 = tid, c1 = tid + 256, c2 = tid + 512;
    for (int i = 0; i < D; ++i) {
        float sx = sc[i], se = ec[i];
        const float* r1 = W2 + (long)i * D;
        const float* r2 = We2 + (long)i * D;
        a0 += sx * r1[c0] + se * r2[c0];
        a1 += sx * r1[c1] + se * r2[c1];
        a2 += sx * r1[c2] + se * r2[c2];
    }
    out[b * D + c0] = a0 + ht[c0] + b2[c0];
    out[b * D + c1] = a1 + ht[c1] + b2[c1];
    out[b * D + c2] = a2 + ht[c2] + b2[c2];
}

extern "C" void kernel_launch(void* const* d_in, const int* in_sizes, int n_in,
                              void* d_out, int out_size, void* d_ws, size_t ws_size,
                              hipStream_t stream) {
    const float* x    = (const float*)d_in[0];
    const float* ef   = (const float*)d_in[1];
    const int*   src  = (const int*)d_in[2];
    const int*   dst  = (const int*)d_in[3];
    const int*   goff = (const int*)d_in[4];
    const float* W1   = (const float*)d_in[5];
    const float* We1  = (const float*)d_in[6];
    const float* al1  = (const float*)d_in[7];
    const float* ar1  = (const float*)d_in[8];
    const float* ae1  = (const float*)d_in[9];
    const float* b1   = (const float*)d_in[10];
    const float* W2   = (const float*)d_in[11];
    const float* We2  = (const float*)d_in[12];
    const float* al2  = (const float*)d_in[13];
    const float* ar2  = (const float*)d_in[14];
    const float* ae2  = (const float*)d_in[15];
    const float* b2   = (const float*)d_in[16];
    float* out = (float*)d_out;

    int E = in_sizes[2];
    int B = in_sizes[4];

    float* ws  = (float*)d_ws;
    float* v   = ws;                       // 6*D floats
    int*   l2e = (int*)(ws + 6 * D);       // B*CAP ints
    int*   cnt = l2e + B * CAP;            // B ints
    float* h_t = (float*)(cnt + B);        // B*D floats
    float* h_s = h_t + (long)B * D;        // B*CAP*D floats

    hipLaunchKernelGGL(projvec, dim3((6 * D + 3) / 4), dim3(256), 0, stream,
                       W1, We1, W2, We2, al1, ar1, ae1, al2, ar2, ae2, v);
    hipLaunchKernelGGL(build_l2, dim3(1), dim3(B * 64), 0, stream, dst, goff, E, l2e, cnt);
    hipLaunchKernelGGL(layer1, dim3(B + B * CAP), dim3(256), 0, stream,
                       x, ef, src, dst, goff, W1, We1, b1, v, l2e, cnt, h_t, h_s, E, B);
    hipLaunchKernelGGL(layer2, dim3(B), dim3(256), 0, stream,
                       ef, W2, We2, b2, v, l2e, cnt, h_t, h_s, out, B);
}

// Round 2
// 348.977 us; speedup vs baseline: 2.2928x; 2.2928x over previous
//
#include <hip/hip_runtime.h>

#define D 768
#define CAP 64      // max layer-2 in-edges per target
#define MAXDEG 128  // max in-degree of any processed node (layer 1)
#define NEG 0.2f

__device__ __forceinline__ float block_reduce_sum(float v, float* scratch) {
    int lane = threadIdx.x & 63;
    int wid  = threadIdx.x >> 6;
    #pragma unroll
    for (int o = 32; o > 0; o >>= 1) v += __shfl_down(v, o, 64);
    if (lane == 0) scratch[wid] = v;
    __syncthreads();
    if (threadIdx.x == 0) {
        float r = 0.f;
        int nw = (blockDim.x + 63) >> 6;
        for (int w = 0; w < nw; ++w) r += scratch[w];
        scratch[0] = r;
    }
    __syncthreads();
    float r = scratch[0];
    __syncthreads();
    return r;
}

// v[which*D + i] = sum_j W[i*D+j] * a[j]  for the 6 (W, a) pairs
__global__ void projvec(const float* W1, const float* We1, const float* W2, const float* We2,
                        const float* al1, const float* ar1, const float* ae1,
                        const float* al2, const float* ar2, const float* ae2,
                        float* v) {
    int task = blockIdx.x * (blockDim.x >> 6) + (threadIdx.x >> 6);
    int lane = threadIdx.x & 63;
    if (task >= 6 * D) return;
    int which = task / D, i = task % D;
    const float* W; const float* a;
    switch (which) {
        case 0: W = W1;  a = al1; break;
        case 1: W = W1;  a = ar1; break;
        case 2: W = We1; a = ae1; break;
        case 3: W = W2;  a = al2; break;
        case 4: W = W2;  a = ar2; break;
        default: W = We2; a = ae2; break;
    }
    float s = 0.f;
    for (int j = lane; j < D; j += 64) s += W[i * D + j] * a[j];
    #pragma unroll
    for (int o = 32; o > 0; o >>= 1) s += __shfl_down(s, o, 64);
    if (lane == 0) v[which * D + i] = s;
}

__global__ void init_cnt(int* cnt, int B) {
    if ((int)threadIdx.x < B) cnt[threadIdx.x] = 0;
}

// grid-stride over all edges; append matches to per-target lists (unsorted)
__global__ __launch_bounds__(256) void build_l2_par(
        const int* __restrict__ dst, const int* __restrict__ goff,
        int E, int B, int* l2e, int* cnt) {
    __shared__ int tg[32];
    if ((int)threadIdx.x < B) tg[threadIdx.x] = goff[threadIdx.x];
    __syncthreads();
    for (int e = blockIdx.x * blockDim.x + threadIdx.x; e < E;
         e += gridDim.x * blockDim.x) {
        int d = dst[e];
        for (int b = 0; b < B; ++b) {
            if (d == tg[b]) {
                int pos = atomicAdd(&cnt[b], 1);
                if (pos < CAP) l2e[b * CAP + pos] = e;
            }
        }
    }
}

// insertion-sort each target's list by edge id -> deterministic order
__global__ void sort_l2(int* l2e, int* cnt, int B) {
    int b = threadIdx.x;
    if (b >= B) return;
    int n = cnt[b]; if (n > CAP) n = CAP; cnt[b] = n;
    int* L = l2e + b * CAP;
    for (int i = 1; i < n; ++i) {
        int k = L[i]; int j = i - 1;
        while (j >= 0 && L[j] > k) { L[j + 1] = L[j]; --j; }
        L[j + 1] = k;
    }
}

// one block per needed layer-1 output row (targets, then L2-edge srcs)
__global__ __launch_bounds__(256) void layer1(
        const float* __restrict__ x, const float* __restrict__ ef,
        const int* __restrict__ src, const int* __restrict__ dst,
        const int* __restrict__ goff,
        const float* __restrict__ W1, const float* __restrict__ We1,
        const float* __restrict__ b1, const float* __restrict__ v,
        const int* __restrict__ l2e, const int* __restrict__ cnt,
        float* h_t, float* h_s, int E, int B) {
    __shared__ float xj[D], sc[D], ec[D];
    __shared__ float red[8];
    __shared__ int   mlist[MAXDEG], msrc[MAXDEG];
    __shared__ float matt[MAXDEG];
    __shared__ int   nm_sh;
    int tid = threadIdx.x;
    int bid = blockIdx.x;
    int j; float* hout;
    if (bid < B) {
        j = goff[bid]; hout = h_t + bid * D;
    } else {
        int flat = bid - B; int b = flat >> 6, i = flat & 63;
        if (b >= B || i >= cnt[b]) return;
        j = src[l2e[b * CAP + i]];
        hout = h_s + (long)flat * D;
    }
    const float* val1 = v;
    const float* var1 = v + D;
    const float* vae1 = v + 2 * D;

    for (int c = tid; c < D; c += 256) xj[c] = x[(long)j * D + c];
    if (tid == 0) nm_sh = 0;
    __syncthreads();

    float p = 0.f;
    for (int c = tid; c < D; c += 256) p += xj[c] * var1[c];
    float er_j = block_reduce_sum(p, red);

    for (int e = tid; e < E; e += 256)
        if (dst[e] == j) { int q = atomicAdd(&nm_sh, 1); if (q < MAXDEG) mlist[q] = e; }
    __syncthreads();
    int nm = nm_sh < MAXDEG ? nm_sh : MAXDEG;
    if (tid == 0) {  // sort by edge id -> deterministic order
        for (int a_ = 1; a_ < nm; ++a_) {
            int key = mlist[a_]; int bq = a_ - 1;
            while (bq >= 0 && mlist[bq] > key) { mlist[bq + 1] = mlist[bq]; --bq; }
            mlist[bq + 1] = key;
        }
        for (int k = 0; k < nm; ++k) msrc[k] = src[mlist[k]];
    }
    __syncthreads();

    for (int k = 0; k < nm; ++k) {
        int e = mlist[k], s_ = msrc[k];
        float q = 0.f;
        for (int c = tid; c < D; c += 256)
            q += x[(long)s_ * D + c] * val1[c] + ef[(long)e * D + c] * vae1[c];
        float tot = block_reduce_sum(q, red);
        if (tid == 0) {
            tot += er_j;
            matt[k] = tot >= 0.f ? tot : NEG * tot;
        }
        __syncthreads();
    }
    if (tid == 0) {
        float m = -1e30f;
        for (int k = 0; k < nm; ++k) m = fmaxf(m, matt[k]);
        float s = 0.f;
        for (int k = 0; k < nm; ++k) { matt[k] = expf(matt[k] - m); s += matt[k]; }
        float inv = 1.f / s;
        for (int k = 0; k < nm; ++k) matt[k] *= inv;
    }
    __syncthreads();

    for (int c = tid; c < D; c += 256) {
        float sx = 0.f, se = 0.f;
        for (int k = 0; k < nm; ++k) {
            sx += matt[k] * x[(long)msrc[k] * D + c];
            se += matt[k] * ef[(long)mlist[k] * D + c];
        }
        sc[c] = sx; ec[c] = se;
    }
    __syncthreads();

    float a0 = 0.f, a1 = 0.f, a2 = 0.f;
    int c0 = tid, c1 = tid + 256, c2 = tid + 512;
    for (int i = 0; i < D; ++i) {
        float sx = sc[i], se = ec[i];
        const float* r1 = W1 + (long)i * D;
        const float* r2 = We1 + (long)i * D;
        a0 += sx * r1[c0] + se * r2[c0];
        a1 += sx * r1[c1] + se * r2[c1];
        a2 += sx * r1[c2] + se * r2[c2];
    }
    float h0 = a0 + xj[c0] + b1[c0]; hout[c0] = h0 > 0.f ? h0 : 0.f;
    float h1 = a1 + xj[c1] + b1[c1]; hout[c1] = h1 > 0.f ? h1 : 0.f;
    float h2 = a2 + xj[c2] + b1[c2]; hout[c2] = h2 > 0.f ? h2 : 0.f;
}

// one block per target: layer-2 attention + aggregate + residual + bias -> d_out
__global__ __launch_bounds__(256) void layer2(
        const float* __restrict__ ef,
        const float* __restrict__ W2, const float* __restrict__ We2,
        const float* __restrict__ b2, const float* __restrict__ v,
        const int* __restrict__ l2e, const int* __restrict__ cnt,
        const float* __restrict__ h_t, const float* __restrict__ h_s,
        float* out, int B) {
    __shared__ float ht[D], sc[D], ec[D];
    __shared__ float red[8];
    __shared__ float matt[CAP];
    int tid = threadIdx.x, b = blockIdx.x;
    const float* val2 = v + 3 * D;
    const float* var2 = v + 4 * D;
    const float* vae2 = v + 5 * D;

    for (int c = tid; c < D; c += 256) ht[c] = h_t[b * D + c];
    __syncthreads();

    float p = 0.f;
    for (int c = tid; c < D; c += 256) p += ht[c] * var2[c];
    float er2 = block_reduce_sum(p, red);

    int deg = cnt[b];
    for (int k = 0; k < deg; ++k) {
        int e = l2e[b * CAP + k];
        const float* hs = h_s + (long)(b * CAP + k) * D;
        float q = 0.f;
        for (int c = tid; c < D; c += 256)
            q += hs[c] * val2[c] + ef[(long)e * D + c] * vae2[c];
        float tot = block_reduce_sum(q, red);
        if (tid == 0) {
            tot += er2;
            matt[k] = tot >= 0.f ? tot : NEG * tot;
        }
        __syncthreads();
    }
    if (tid == 0) {
        float m = -1e30f;
        for (int k = 0; k < deg; ++k) m = fmaxf(m, matt[k]);
        float s = 0.f;
        for (int k = 0; k < deg; ++k) { matt[k] = expf(matt[k] - m); s += matt[k]; }
        float inv = 1.f / s;
        for (int k = 0; k < deg; ++k) matt[k] *= inv;
    }
    __syncthreads();

    for (int c = tid; c < D; c += 256) {
        float sx = 0.f, se = 0.f;
        for (int k = 0; k < deg; ++k) {
            sx += matt[k] * h_s[(long)(b * CAP + k) * D + c];
            se += matt[k] * ef[(long)l2e[b * CAP + k] * D + c];
        }
        sc[c] = sx; ec[c] = se;
    }
    __syncthreads();

    float a0 = 0.f, a1 = 0.f, a2 = 0.f;
    int c0 = tid, c1 = tid + 256, c2 = tid + 512;
    for (int i = 0; i < D; ++i) {
        float sx = sc[i], se = ec[i];
        const float* r1 = W2 + (long)i * D;
        const float* r2 = We2 + (long)i * D;
        a0 += sx * r1[c0] + se * r2[c0];
        a1 += sx * r1[c1] + se * r2[c1];
        a2 += sx * r1[c2] + se * r2[c2];
    }
    out[b * D + c0] = a0 + ht[c0] + b2[c0];
    out[b * D + c1] = a1 + ht[c1] + b2[c1];
    out[b * D + c2] = a2 + ht[c2] + b2[c2];
}

extern "C" void kernel_launch(void* const* d_in, const int* in_sizes, int n_in,
                              void* d_out, int out_size, void* d_ws, size_t ws_size,
                              hipStream_t stream) {
    const float* x    = (const float*)d_in[0];
    const float* ef   = (const float*)d_in[1];
    const int*   src  = (const int*)d_in[2];
    const int*   dst  = (const int*)d_in[3];
    const int*   goff = (const int*)d_in[4];
    const float* W1   = (const float*)d_in[5];
    const float* We1  = (const float*)d_in[6];
    const float* al1  = (const float*)d_in[7];
    const float* ar1  = (const float*)d_in[8];
    const float* ae1  = (const float*)d_in[9];
    const float* b1   = (const float*)d_in[10];
    const float* W2   = (const float*)d_in[11];
    const float* We2  = (const float*)d_in[12];
    const float* al2  = (const float*)d_in[13];
    const float* ar2  = (const float*)d_in[14];
    const float* ae2  = (const float*)d_in[15];
    const float* b2   = (const float*)d_in[16];
    float* out = (float*)d_out;

    int E = in_sizes[2];
    int B = in_sizes[4];

    float* ws  = (float*)d_ws;
    float* v   = ws;                       // 6*D floats
    int*   l2e = (int*)(ws + 6 * D);       // B*CAP ints
    int*   cnt = l2e + B * CAP;            // B ints
    float* h_t = (float*)(cnt + B);        // B*D floats
    float* h_s = h_t + (long)B * D;        // B*CAP*D floats

    hipLaunchKernelGGL(init_cnt, dim3(1), dim3(64), 0, stream, cnt, B);
    hipLaunchKernelGGL(projvec, dim3((6 * D + 3) / 4), dim3(256), 0, stream,
                       W1, We1, W2, We2, al1, ar1, ae1, al2, ar2, ae2, v);
    hipLaunchKernelGGL(build_l2_par, dim3((E + 255) / 256), dim3(256), 0, stream,
                       dst, goff, E, B, l2e, cnt);
    hipLaunchKernelGGL(sort_l2, dim3(1), dim3(64), 0, stream, l2e, cnt, B);
    hipLaunchKernelGGL(layer1, dim3(B + B * CAP), dim3(256), 0, stream,
                       x, ef, src, dst, goff, W1, We1, b1, v, l2e, cnt, h_t, h_s, E, B);
    hipLaunchKernelGGL(layer2, dim3(B), dim3(256), 0, stream,
                       ef, W2, We2, b2, v, l2e, cnt, h_t, h_s, out, B);
}

// Round 3
// 140.178 us; speedup vs baseline: 5.7079x; 2.4895x over previous
//
#include <hip/hip_runtime.h>

#define D 768
#define CAP 64        // max layer-2 in-edges per target
#define MD1 32        // max in-degree for layer-1 match lists (Poisson(1)+1 -> ~30 sigma)
#define MAXROWS 1040  // B + B*CAP worst case
#define NEG 0.2f

__device__ __forceinline__ float block_reduce_sum(float v, float* scratch) {
    int lane = threadIdx.x & 63;
    int wid  = threadIdx.x >> 6;
    #pragma unroll
    for (int o = 32; o > 0; o >>= 1) v += __shfl_down(v, o, 64);
    if (lane == 0) scratch[wid] = v;
    __syncthreads();
    if (threadIdx.x == 0) {
        float r = 0.f;
        int nw = (blockDim.x + 63) >> 6;
        for (int w = 0; w < nw; ++w) r += scratch[w];
        scratch[0] = r;
    }
    __syncthreads();
    float r = scratch[0];
    __syncthreads();
    return r;
}

// v[which*D + i] = sum_j W[i*D+j] * a[j]  for the 6 (W, a) pairs
__global__ void projvec(const float* W1, const float* We1, const float* W2, const float* We2,
                        const float* al1, const float* ar1, const float* ae1,
                        const float* al2, const float* ar2, const float* ae2,
                        float* v) {
    int task = blockIdx.x * (blockDim.x >> 6) + (threadIdx.x >> 6);
    int lane = threadIdx.x & 63;
    if (task >= 6 * D) return;
    int which = task / D, i = task % D;
    const float* W; const float* a;
    switch (which) {
        case 0: W = W1;  a = al1; break;
        case 1: W = W1;  a = ar1; break;
        case 2: W = We1; a = ae1; break;
        case 3: W = W2;  a = al2; break;
        case 4: W = W2;  a = ar2; break;
        default: W = We2; a = ae2; break;
    }
    float s = 0.f;
    for (int j = lane; j < D; j += 64) s += W[i * D + j] * a[j];
    #pragma unroll
    for (int o = 32; o > 0; o >>= 1) s += __shfl_down(s, o, 64);
    if (lane == 0) v[which * D + i] = s;
}

__global__ void init_cnt(int* cnt, int B, int* mcnt, int nrows) {
    for (int i = threadIdx.x; i < B; i += 256) cnt[i] = 0;
    for (int i = threadIdx.x; i < nrows; i += 256) mcnt[i] = 0;
}

// grid-stride over all edges; append matches to per-target lists (unsorted)
__global__ __launch_bounds__(256) void build_l2_par(
        const int* __restrict__ dst, const int* __restrict__ goff,
        int E, int B, int* l2e, int* cnt) {
    __shared__ int tg[32];
    if ((int)threadIdx.x < B) tg[threadIdx.x] = goff[threadIdx.x];
    __syncthreads();
    for (int e = blockIdx.x * blockDim.x + threadIdx.x; e < E;
         e += gridDim.x * blockDim.x) {
        int d = dst[e];
        for (int b = 0; b < B; ++b) {
            if (d == tg[b]) {
                int pos = atomicAdd(&cnt[b], 1);
                if (pos < CAP) l2e[b * CAP + pos] = e;
            }
        }
    }
}

// single wave: sort l2 lists by edge id, then ballot-compact the valid slots
// slot s: [0,B) = target nodes; B + b*CAP + i = src of i-th l2 edge of target b
__global__ void compact_rows(const int* __restrict__ src, const int* __restrict__ goff,
                             int* l2e, int* cnt, int* cnode, int* cslot, int* Mp, int B) {
    int t = threadIdx.x;  // 64 threads = 1 wave
    if (t < B) {
        int n = cnt[t]; if (n > CAP) n = CAP; cnt[t] = n;
        int* L = l2e + t * CAP;
        for (int i = 1; i < n; ++i) {
            int k = L[i]; int j = i - 1;
            while (j >= 0 && L[j] > k) { L[j + 1] = L[j]; --j; }
            L[j + 1] = k;
        }
    }
    __syncthreads();
    int nslot = B + B * CAP;
    int base = 0;
    for (int s0 = 0; s0 < nslot; s0 += 64) {
        int s = s0 + t;
        bool valid = false; int node = -1;
        if (s < B) { valid = true; node = goff[s]; }
        else if (s < nslot) {
            int rb = (s - B) >> 6, i = (s - B) & 63;   // CAP == 64
            if (i < cnt[rb]) { valid = true; node = src[l2e[rb * CAP + i]]; }
        }
        unsigned long long m = __ballot(valid);
        if (valid) {
            int ci = base + __popcll(m & ((1ULL << t) - 1));
            cnode[ci] = node; cslot[ci] = s;
        }
        base += __popcll(m);
    }
    if (t == 0) *Mp = base;
}

// grid-stride over edges; match dst against the compact node set (in LDS)
__global__ __launch_bounds__(256) void match_l1(
        const int* __restrict__ dst, const int* __restrict__ cnode, const int* __restrict__ Mp,
        int E, int* medge, int* mcnt) {
    __shared__ int nodes[MAXROWS];
    int M = *Mp;
    for (int i = threadIdx.x; i < M; i += 256) nodes[i] = cnode[i];
    __syncthreads();
    for (int e = blockIdx.x * blockDim.x + threadIdx.x; e < E;
         e += gridDim.x * blockDim.x) {
        int d = dst[e];
        for (int c = 0; c < M; ++c) {
            if (nodes[c] == d) {
                int p = atomicAdd(&mcnt[c], 1);
                if (p < MD1) medge[c * MD1 + p] = e;
            }
        }
    }
}

// one thread per compact row: sort match list by edge id, gather srcs
__global__ void sort_ml(const int* __restrict__ src, int* medge, int* mcnt, int* msrc,
                        const int* __restrict__ Mp) {
    int c = blockIdx.x * blockDim.x + threadIdx.x;
    if (c >= *Mp) return;
    int n = mcnt[c]; if (n > MD1) n = MD1; mcnt[c] = n;
    int* L = medge + c * MD1;
    for (int i = 1; i < n; ++i) {
        int k = L[i]; int j = i - 1;
        while (j >= 0 && L[j] > k) { L[j + 1] = L[j]; --j; }
        L[j + 1] = k;
    }
    for (int k = 0; k < n; ++k) msrc[c * MD1 + k] = src[L[k]];
}

// layer-1 EdgeGAT for one needed row, one 256-col output chunk per block
__global__ __launch_bounds__(256) void gemv1(
        const float* __restrict__ x, const float* __restrict__ ef,
        const float* __restrict__ W1, const float* __restrict__ We1,
        const float* __restrict__ b1, const float* __restrict__ v,
        const int* __restrict__ cnode, const int* __restrict__ cslot,
        const int* __restrict__ Mp,
        const int* __restrict__ medge, const int* __restrict__ mcnt,
        const int* __restrict__ msrc,
        float* h_t, float* h_s, int B) {
    int c = blockIdx.y;
    if (c >= *Mp) return;
    int q = blockIdx.x, tid = threadIdx.x;
    int j = cnode[c], slot = cslot[c];
    int nm = mcnt[c];
    __shared__ float xj[D], sc[D], ec[D];
    __shared__ float red[8];
    __shared__ float matt[MD1];
    const float* val1 = v;
    const float* var1 = v + D;
    const float* vae1 = v + 2 * D;

    for (int cc = tid; cc < D; cc += 256) xj[cc] = x[(long)j * D + cc];
    __syncthreads();

    float p = 0.f;
    for (int cc = tid; cc < D; cc += 256) p += xj[cc] * var1[cc];
    float er_j = block_reduce_sum(p, red);

    for (int k = 0; k < nm; ++k) {
        int e = medge[c * MD1 + k], s_ = msrc[c * MD1 + k];
        float qq = 0.f;
        for (int cc = tid; cc < D; cc += 256)
            qq += x[(long)s_ * D + cc] * val1[cc] + ef[(long)e * D + cc] * vae1[cc];
        float tot = block_reduce_sum(qq, red);
        if (tid == 0) {
            tot += er_j;
            matt[k] = tot >= 0.f ? tot : NEG * tot;
        }
    }
    __syncthreads();
    if (tid == 0) {
        float m = -1e30f;
        for (int k = 0; k < nm; ++k) m = fmaxf(m, matt[k]);
        float s = 0.f;
        for (int k = 0; k < nm; ++k) { matt[k] = expf(matt[k] - m); s += matt[k]; }
        float inv = 1.f / s;
        for (int k = 0; k < nm; ++k) matt[k] *= inv;
    }
    __syncthreads();

    for (int cc = tid; cc < D; cc += 256) {
        float sx = 0.f, se = 0.f;
        for (int k = 0; k < nm; ++k) {
            sx += matt[k] * x[(long)msrc[c * MD1 + k] * D + cc];
            se += matt[k] * ef[(long)medge[c * MD1 + k] * D + cc];
        }
        sc[cc] = sx; ec[cc] = se;
    }
    __syncthreads();

    int col = q * 256 + tid;
    float a0 = 0.f;
    for (int i = 0; i < D; ++i)
        a0 += sc[i] * W1[(long)i * D + col] + ec[i] * We1[(long)i * D + col];
    float h = a0 + xj[col] + b1[col];
    float* hout = (slot < B) ? (h_t + (long)slot * D) : (h_s + (long)(slot - B) * D);
    hout[col] = h > 0.f ? h : 0.f;
}

// layer-2 EdgeGAT for one target, one 256-col output chunk per block
__global__ __launch_bounds__(256) void gemv2(
        const float* __restrict__ ef,
        const float* __restrict__ W2, const float* __restrict__ We2,
        const float* __restrict__ b2, const float* __restrict__ v,
        const int* __restrict__ l2e, const int* __restrict__ cnt,
        const float* __restrict__ h_t, const float* __restrict__ h_s,
        float* out, int B) {
    int b = blockIdx.y, q = blockIdx.x, tid = threadIdx.x;
    __shared__ float ht[D], sc[D], ec[D];
    __shared__ float red[8];
    __shared__ float matt[CAP];
    const float* val2 = v + 3 * D;
    const float* var2 = v + 4 * D;
    const float* vae2 = v + 5 * D;

    for (int cc = tid; cc < D; cc += 256) ht[cc] = h_t[(long)b * D + cc];
    __syncthreads();

    float p = 0.f;
    for (int cc = tid; cc < D; cc += 256) p += ht[cc] * var2[cc];
    float er2 = block_reduce_sum(p, red);

    int deg = cnt[b];
    for (int k = 0; k < deg; ++k) {
        int e = l2e[b * CAP + k];
        const float* hs = h_s + (long)(b * CAP + k) * D;
        float qq = 0.f;
        for (int cc = tid; cc < D; cc += 256)
            qq += hs[cc] * val2[cc] + ef[(long)e * D + cc] * vae2[cc];
        float tot = block_reduce_sum(qq, red);
        if (tid == 0) {
            tot += er2;
            matt[k] = tot >= 0.f ? tot : NEG * tot;
        }
    }
    __syncthreads();
    if (tid == 0) {
        float m = -1e30f;
        for (int k = 0; k < deg; ++k) m = fmaxf(m, matt[k]);
        float s = 0.f;
        for (int k = 0; k < deg; ++k) { matt[k] = expf(matt[k] - m); s += matt[k]; }
        float inv = 1.f / s;
        for (int k = 0; k < deg; ++k) matt[k] *= inv;
    }
    __syncthreads();

    for (int cc = tid; cc < D; cc += 256) {
        float sx = 0.f, se = 0.f;
        for (int k = 0; k < deg; ++k) {
            sx += matt[k] * h_s[(long)(b * CAP + k) * D + cc];
            se += matt[k] * ef[(long)l2e[b * CAP + k] * D + cc];
        }
        sc[cc] = sx; ec[cc] = se;
    }
    __syncthreads();

    int col = q * 256 + tid;
    float a0 = 0.f;
    for (int i = 0; i < D; ++i)
        a0 += sc[i] * W2[(long)i * D + col] + ec[i] * We2[(long)i * D + col];
    out[(long)b * D + col] = a0 + ht[col] + b2[col];
}

extern "C" void kernel_launch(void* const* d_in, const int* in_sizes, int n_in,
                              void* d_out, int out_size, void* d_ws, size_t ws_size,
                              hipStream_t stream) {
    const float* x    = (const float*)d_in[0];
    const float* ef   = (const float*)d_in[1];
    const int*   src  = (const int*)d_in[2];
    const int*   dst  = (const int*)d_in[3];
    const int*   goff = (const int*)d_in[4];
    const float* W1   = (const float*)d_in[5];
    const float* We1  = (const float*)d_in[6];
    const float* al1  = (const float*)d_in[7];
    const float* ar1  = (const float*)d_in[8];
    const float* ae1  = (const float*)d_in[9];
    const float* b1   = (const float*)d_in[10];
    const float* W2   = (const float*)d_in[11];
    const float* We2  = (const float*)d_in[12];
    const float* al2  = (const float*)d_in[13];
    const float* ar2  = (const float*)d_in[14];
    const float* ae2  = (const float*)d_in[15];
    const float* b2   = (const float*)d_in[16];
    float* out = (float*)d_out;

    int E = in_sizes[2];
    int B = in_sizes[4];
    int nrows = B + B * CAP;   // 1040

    float* ws   = (float*)d_ws;
    float* v    = ws;                          // 6*D floats
    int*   l2e  = (int*)(ws + 6 * D);          // B*CAP
    int*   cnt  = l2e + B * CAP;               // B
    int*   Mp   = cnt + B;                     // 1
    int*   cnode= Mp + 1;                      // nrows
    int*   cslot= cnode + nrows;               // nrows
    int*   mcnt = cslot + nrows;               // nrows
    int*   medge= mcnt + nrows;                // nrows*MD1
    int*   msrc = medge + nrows * MD1;         // nrows*MD1
    float* h_t  = (float*)(msrc + nrows * MD1);// B*D
    float* h_s  = h_t + (long)B * D;           // B*CAP*D

    hipLaunchKernelGGL(init_cnt, dim3(1), dim3(256), 0, stream, cnt, B, mcnt, nrows);
    hipLaunchKernelGGL(projvec, dim3((6 * D + 3) / 4), dim3(256), 0, stream,
                       W1, We1, W2, We2, al1, ar1, ae1, al2, ar2, ae2, v);
    hipLaunchKernelGGL(build_l2_par, dim3((E + 255) / 256), dim3(256), 0, stream,
                       dst, goff, E, B, l2e, cnt);
    hipLaunchKernelGGL(compact_rows, dim3(1), dim3(64), 0, stream,
                       src, goff, l2e, cnt, cnode, cslot, Mp, B);
    hipLaunchKernelGGL(match_l1, dim3((E + 255) / 256), dim3(256), 0, stream,
                       dst, cnode, Mp, E, medge, mcnt);
    hipLaunchKernelGGL(sort_ml, dim3((nrows + 255) / 256), dim3(256), 0, stream,
                       src, medge, mcnt, msrc, Mp);
    hipLaunchKernelGGL(gemv1, dim3(3, nrows), dim3(256), 0, stream,
                       x, ef, W1, We1, b1, v, cnode, cslot, Mp, medge, mcnt, msrc,
                       h_t, h_s, B);
    hipLaunchKernelGGL(gemv2, dim3(3, B), dim3(256), 0, stream,
                       ef, W2, We2, b2, v, l2e, cnt, h_t, h_s, out, B);
}

// Round 4
// 95.598 us; speedup vs baseline: 8.3697x; 1.4663x over previous
//
#include <hip/hip_runtime.h>

#define D 768
#define CAP 64        // max layer-2 in-edges per target
#define MD1 32        // max in-degree for layer-1 match lists
#define MAXROWS 1040  // B + B*CAP worst case (B=16)
#define NI 24         // i-chunks in gemm_big (768 = 24*32)
#define IC 32         // i-chunk depth
#define NEG 0.2f

__device__ __forceinline__ float block_reduce_sum(float v, float* scratch) {
    int lane = threadIdx.x & 63;
    int wid  = threadIdx.x >> 6;
    #pragma unroll
    for (int o = 32; o > 0; o >>= 1) v += __shfl_down(v, o, 64);
    if (lane == 0) scratch[wid] = v;
    __syncthreads();
    if (threadIdx.x == 0) {
        float r = 0.f;
        int nw = (blockDim.x + 63) >> 6;
        for (int w = 0; w < nw; ++w) r += scratch[w];
        scratch[0] = r;
    }
    __syncthreads();
    float r = scratch[0];
    __syncthreads();
    return r;
}

// v[0]=W1@al1 v[1]=W1@ar1 v[2]=We1@ae1 v[3]=W2@al2 v[4]=W2@ar2 v[5]=We2@ae2 (D each)
__global__ void projvec(const float* W1, const float* We1, const float* W2, const float* We2,
                        const float* al1, const float* ar1, const float* ae1,
                        const float* al2, const float* ar2, const float* ae2,
                        float* v) {
    int task = blockIdx.x * 4 + (threadIdx.x >> 6);
    int lane = threadIdx.x & 63;
    if (task >= 4 * D) return;
    int g = task / D, i = task % D;
    const float* W; const float* a; const float* a2 = nullptr; int o1, o2 = 0;
    switch (g) {
        case 0: W = W1;  a = al1; a2 = ar1; o1 = 0;     o2 = D;     break;
        case 1: W = We1; a = ae1;           o1 = 2 * D;             break;
        case 2: W = W2;  a = al2; a2 = ar2; o1 = 3 * D; o2 = 4 * D; break;
        default:W = We2; a = ae2;           o1 = 5 * D;             break;
    }
    float s1 = 0.f, s2 = 0.f;
    for (int j = lane; j < D; j += 64) {
        float w = W[(long)i * D + j];
        s1 += w * a[j];
        if (a2) s2 += w * a2[j];
    }
    #pragma unroll
    for (int o = 32; o > 0; o >>= 1) { s1 += __shfl_down(s1, o, 64); s2 += __shfl_down(s2, o, 64); }
    if (lane == 0) { v[o1 + i] = s1; if (a2) v[o2 + i] = s2; }
}

__global__ void init_cnt(int* p, int n) {  // zero [cnt | Mp | mcnt] span
    for (int i = threadIdx.x; i < n; i += 256) p[i] = 0;
}

// grid-stride over all edges; append matches to per-target lists (unsorted)
__global__ __launch_bounds__(256) void build_l2_par(
        const int* __restrict__ dst, const int* __restrict__ goff,
        int E, int B, int* l2e, int* cnt) {
    __shared__ int tg[32];
    if ((int)threadIdx.x < B) tg[threadIdx.x] = goff[threadIdx.x];
    __syncthreads();
    for (int e = blockIdx.x * blockDim.x + threadIdx.x; e < E;
         e += gridDim.x * blockDim.x) {
        int d = dst[e];
        for (int b = 0; b < B; ++b) {
            if (d == tg[b]) {
                int pos = atomicAdd(&cnt[b], 1);
                if (pos < CAP) l2e[b * CAP + pos] = e;
            }
        }
    }
}

// single wave: sort l2 lists by edge id, then ballot-compact valid slots.
// slot s: [0,B) = target b; B + b*CAP + i = src of i-th l2 edge of target b
__global__ void compact_rows(const int* __restrict__ src, const int* __restrict__ goff,
                             int* l2e, int* cnt, int* cnode, int* cslot, int* Mp, int B) {
    int t = threadIdx.x;  // 64 threads = 1 wave
    if (t < B) {
        int n = cnt[t]; if (n > CAP) n = CAP; cnt[t] = n;
        int* L = l2e + t * CAP;
        for (int i = 1; i < n; ++i) {
            int k = L[i]; int j = i - 1;
            while (j >= 0 && L[j] > k) { L[j + 1] = L[j]; --j; }
            L[j + 1] = k;
        }
    }
    __syncthreads();
    int nslot = B + B * CAP;
    int base = 0;
    for (int s0 = 0; s0 < nslot; s0 += 64) {
        int s = s0 + t;
        bool valid = false; int node = -1;
        if (s < B) { valid = true; node = goff[s]; }
        else if (s < nslot) {
            int rb = (s - B) >> 6, i = (s - B) & 63;   // CAP == 64
            if (i < cnt[rb]) { valid = true; node = src[l2e[rb * CAP + i]]; }
        }
        unsigned long long m = __ballot(valid);
        if (valid) {
            int ci = base + __popcll(m & ((1ULL << t) - 1));
            cnode[ci] = node; cslot[ci] = s;
        }
        base += __popcll(m);
    }
    if (t == 0) *Mp = base;
}

// grid-stride over edges; match dst against the compact node set (in LDS)
__global__ __launch_bounds__(256) void match_l1(
        const int* __restrict__ dst, const int* __restrict__ cnode, const int* __restrict__ Mp,
        int E, int* medge, int* mcnt) {
    __shared__ int nodes[MAXROWS];
    int M = *Mp;
    for (int i = threadIdx.x; i < M; i += 256) nodes[i] = cnode[i];
    __syncthreads();
    for (int e = blockIdx.x * blockDim.x + threadIdx.x; e < E;
         e += gridDim.x * blockDim.x) {
        int d = dst[e];
        for (int c = 0; c < M; ++c) {
            if (nodes[c] == d) {
                int p = atomicAdd(&mcnt[c], 1);
                if (p < MD1) medge[c * MD1 + p] = e;
            }
        }
    }
}

// layer-1 attention + aggregation for one compact row -> aggS/aggE
__global__ __launch_bounds__(256) void agg1(
        const float* __restrict__ x, const float* __restrict__ ef,
        const int* __restrict__ src, const float* __restrict__ v,
        const int* __restrict__ cnode, const int* __restrict__ Mp,
        int* medge, const int* __restrict__ mcnt,
        float* aggS, float* aggE) {
    int c = blockIdx.x;
    if (c >= *Mp) return;
    int tid = threadIdx.x;
    __shared__ float red[8];
    __shared__ float matt[MD1];
    __shared__ int ms[MD1], me[MD1];
    int nm = mcnt[c]; if (nm > MD1) nm = MD1;
    int j = cnode[c];
    if (tid == 0) {  // sort by edge id -> deterministic
        int* L = medge + c * MD1;
        for (int a_ = 1; a_ < nm; ++a_) {
            int k = L[a_]; int b = a_ - 1;
            while (b >= 0 && L[b] > k) { L[b + 1] = L[b]; --b; }
            L[b + 1] = k;
        }
        for (int k = 0; k < nm; ++k) { me[k] = L[k]; ms[k] = src[L[k]]; }
    }
    __syncthreads();
    const float* val1 = v;
    const float* var1 = v + D;
    const float* vae1 = v + 2 * D;
    float p = 0.f;
    for (int cc = tid; cc < D; cc += 256) p += x[(long)j * D + cc] * var1[cc];
    float er_j = block_reduce_sum(p, red);
    for (int k = 0; k < nm; ++k) {
        float q = 0.f;
        for (int cc = tid; cc < D; cc += 256)
            q += x[(long)ms[k] * D + cc] * val1[cc] + ef[(long)me[k] * D + cc] * vae1[cc];
        float tot = block_reduce_sum(q, red);
        if (tid == 0) {
            tot += er_j;
            matt[k] = tot >= 0.f ? tot : NEG * tot;
        }
    }
    __syncthreads();
    if (tid == 0) {
        float m = -1e30f;
        for (int k = 0; k < nm; ++k) m = fmaxf(m, matt[k]);
        float s = 0.f;
        for (int k = 0; k < nm; ++k) { matt[k] = expf(matt[k] - m); s += matt[k]; }
        float inv = s > 0.f ? 1.f / s : 0.f;
        for (int k = 0; k < nm; ++k) matt[k] *= inv;
    }
    __syncthreads();
    for (int cc = tid; cc < D; cc += 256) {
        float sx = 0.f, se = 0.f;
        for (int k = 0; k < nm; ++k) {
            sx += matt[k] * x[(long)ms[k] * D + cc];
            se += matt[k] * ef[(long)me[k] * D + cc];
        }
        aggS[(long)c * D + cc] = sx;
        aggE[(long)c * D + cc] = se;
    }
}

// layer-2 attention + aggregation for one target -> agg2S/agg2E
__global__ __launch_bounds__(256) void agg2(
        const float* __restrict__ ef, const float* __restrict__ v,
        const int* __restrict__ l2e, const int* __restrict__ cnt,
        const float* __restrict__ h_t, const float* __restrict__ h_s,
        float* aggS, float* aggE, int B) {
    int b = blockIdx.x, tid = threadIdx.x;
    __shared__ float red[8];
    __shared__ float matt[CAP];
    const float* val2 = v + 3 * D;
    const float* var2 = v + 4 * D;
    const float* vae2 = v + 5 * D;
    float p = 0.f;
    for (int cc = tid; cc < D; cc += 256) p += h_t[(long)b * D + cc] * var2[cc];
    float er2 = block_reduce_sum(p, red);
    int deg = cnt[b];
    for (int k = 0; k < deg; ++k) {
        int e = l2e[b * CAP + k];
        const float* hs = h_s + (long)(b * CAP + k) * D;
        float q = 0.f;
        for (int cc = tid; cc < D; cc += 256)
            q += hs[cc] * val2[cc] + ef[(long)e * D + cc] * vae2[cc];
        float tot = block_reduce_sum(q, red);
        if (tid == 0) {
            tot += er2;
            matt[k] = tot >= 0.f ? tot : NEG * tot;
        }
    }
    __syncthreads();
    if (tid == 0) {
        float m = -1e30f;
        for (int k = 0; k < deg; ++k) m = fmaxf(m, matt[k]);
        float s = 0.f;
        for (int k = 0; k < deg; ++k) { matt[k] = expf(matt[k] - m); s += matt[k]; }
        float inv = s > 0.f ? 1.f / s : 0.f;
        for (int k = 0; k < deg; ++k) matt[k] *= inv;
    }
    __syncthreads();
    for (int cc = tid; cc < D; cc += 256) {
        float sx = 0.f, se = 0.f;
        for (int k = 0; k < deg; ++k) {
            sx += matt[k] * h_s[(long)(b * CAP + k) * D + cc];
            se += matt[k] * ef[(long)l2e[b * CAP + k] * D + cc];
        }
        aggS[(long)b * D + cc] = sx;
        aggE[(long)b * D + cc] = se;
    }
}

// weight-stationary partial GEMM: partial[by][r][col] = sum_{i in chunk by}
//   aggS[r][i]*W[i][col] + aggE[r][i]*We[i][col]
// grid (3, NI), 256 thr. W tile kept in 64 VGPRs; agg reads are uniform -> s_load.
__global__ __launch_bounds__(256) void gemm_big(
        const float* __restrict__ W, const float* __restrict__ We,
        const float* __restrict__ aggS, const float* __restrict__ aggE,
        const int* __restrict__ Mp, int Mconst, int Rmax,
        float* __restrict__ partial) {
    int col = blockIdx.x * 256 + threadIdx.x;
    int i0  = blockIdx.y * IC;
    int M = Mp ? *Mp : Mconst;
    float w[IC], we[IC];
    #pragma unroll
    for (int k = 0; k < IC; ++k) {
        w[k]  = W[(long)(i0 + k) * D + col];
        we[k] = We[(long)(i0 + k) * D + col];
    }
    float* pout = partial + (long)blockIdx.y * Rmax * D + col;
    for (int r = 0; r < M; ++r) {
        const float* pS = aggS + (long)r * D + i0;
        const float* pE = aggE + (long)r * D + i0;
        float acc = 0.f;
        #pragma unroll
        for (int k = 0; k < IC; ++k) acc += pS[k] * w[k] + pE[k] * we[k];
        pout[(long)r * D] = acc;
    }
}

// reduce partials + residual + bias (+relu) -> h_t/h_s
__global__ __launch_bounds__(256) void epi1(
        const float* __restrict__ partial, const float* __restrict__ x,
        const float* __restrict__ b1,
        const int* __restrict__ cnode, const int* __restrict__ cslot,
        const int* __restrict__ Mp,
        float* h_t, float* h_s, int Rmax, int B) {
    int c = blockIdx.y;
    if (c >= *Mp) return;
    int col = blockIdx.x * 256 + threadIdx.x;
    float acc = 0.f;
    for (int by = 0; by < NI; ++by) acc += partial[((long)by * Rmax + c) * D + col];
    int j = cnode[c], slot = cslot[c];
    float h = acc + x[(long)j * D + col] + b1[col];
    h = h > 0.f ? h : 0.f;
    float* dst = (slot < B) ? (h_t + (long)slot * D) : (h_s + (long)(slot - B) * D);
    dst[col] = h;
}

__global__ __launch_bounds__(256) void epi2(
        const float* __restrict__ partial, const float* __restrict__ h_t,
        const float* __restrict__ b2, float* out, int B) {
    int b = blockIdx.y;
    int col = blockIdx.x * 256 + threadIdx.x;
    float acc = 0.f;
    for (int by = 0; by < NI; ++by) acc += partial[((long)by * B + b) * D + col];
    out[(long)b * D + col] = acc + h_t[(long)b * D + col] + b2[col];
}

extern "C" void kernel_launch(void* const* d_in, const int* in_sizes, int n_in,
                              void* d_out, int out_size, void* d_ws, size_t ws_size,
                              hipStream_t stream) {
    const float* x    = (const float*)d_in[0];
    const float* ef   = (const float*)d_in[1];
    const int*   src  = (const int*)d_in[2];
    const int*   dst  = (const int*)d_in[3];
    const int*   goff = (const int*)d_in[4];
    const float* W1   = (const float*)d_in[5];
    const float* We1  = (const float*)d_in[6];
    const float* al1  = (const float*)d_in[7];
    const float* ar1  = (const float*)d_in[8];
    const float* ae1  = (const float*)d_in[9];
    const float* b1   = (const float*)d_in[10];
    const float* W2   = (const float*)d_in[11];
    const float* We2  = (const float*)d_in[12];
    const float* al2  = (const float*)d_in[13];
    const float* ar2  = (const float*)d_in[14];
    const float* ae2  = (const float*)d_in[15];
    const float* b2   = (const float*)d_in[16];
    float* out = (float*)d_out;

    int E = in_sizes[2];
    int B = in_sizes[4];
    int nrows = B + B * CAP;   // 1040

    float* ws    = (float*)d_ws;
    float* v     = ws;                              // 6*D
    int*   l2e   = (int*)(v + 6 * D);               // B*CAP
    int*   cnt   = l2e + B * CAP;                   // B   } zeroed as one span
    int*   Mp    = cnt + B;                         // 1   }
    int*   mcnt  = Mp + 1;                          // nrows }
    int*   cnode = mcnt + nrows;                    // nrows
    int*   cslot = cnode + nrows;                   // nrows
    int*   medge = cslot + nrows;                   // nrows*MD1
    float* aggS  = (float*)(medge + nrows * MD1);   // nrows*D
    float* aggE  = aggS + (long)nrows * D;          // nrows*D
    float* ag2S  = aggE + (long)nrows * D;          // B*D
    float* ag2E  = ag2S + (long)B * D;              // B*D
    float* h_t   = ag2E + (long)B * D;              // B*D
    float* h_s   = h_t + (long)B * D;               // B*CAP*D
    float* part1 = h_s + (long)B * CAP * D;         // NI*nrows*D (~77 MB worst)
    float* part2 = part1 + (long)NI * nrows * D;    // NI*B*D

    hipLaunchKernelGGL(init_cnt, dim3(1), dim3(256), 0, stream, cnt, B + 1 + nrows);
    hipLaunchKernelGGL(projvec, dim3(4 * D / 4), dim3(256), 0, stream,
                       W1, We1, W2, We2, al1, ar1, ae1, al2, ar2, ae2, v);
    hipLaunchKernelGGL(build_l2_par, dim3((E + 255) / 256), dim3(256), 0, stream,
                       dst, goff, E, B, l2e, cnt);
    hipLaunchKernelGGL(compact_rows, dim3(1), dim3(64), 0, stream,
                       src, goff, l2e, cnt, cnode, cslot, Mp, B);
    hipLaunchKernelGGL(match_l1, dim3((E + 255) / 256), dim3(256), 0, stream,
                       dst, cnode, Mp, E, medge, mcnt);
    hipLaunchKernelGGL(agg1, dim3(nrows), dim3(256), 0, stream,
                       x, ef, src, v, cnode, Mp, medge, mcnt, aggS, aggE);
    hipLaunchKernelGGL(gemm_big, dim3(3, NI), dim3(256), 0, stream,
                       W1, We1, aggS, aggE, (const int*)Mp, 0, nrows, part1);
    hipLaunchKernelGGL(epi1, dim3(3, nrows), dim3(256), 0, stream,
                       part1, x, b1, cnode, cslot, Mp, h_t, h_s, nrows, B);
    hipLaunchKernelGGL(agg2, dim3(B), dim3(256), 0, stream,
                       ef, v, l2e, cnt, h_t, h_s, ag2S, ag2E, B);
    hipLaunchKernelGGL(gemm_big, dim3(3, NI), dim3(256), 0, stream,
                       W2, We2, ag2S, ag2E, (const int*)nullptr, B, B, part2);
    hipLaunchKernelGGL(epi2, dim3(3, B), dim3(256), 0, stream,
                       part2, h_t, b2, out, B);
}